// Round 10
// baseline (284.760 us; speedup 1.0000x reference)
//
#include <hip/hip_runtime.h>
#include <hip/hip_bf16.h>

// Problem constants
#define BB 32
#define CIN 96
#define TT 288
#define VV 25
#define SS 3
#define COUT 96
#define WSZ 5
#define BN_EPS 1e-5f
#define TV (TT*VV)              // 7200
#define KK 288                  // fused GEMM K = s*96+i
#define XCOLS 50                // XAtile rows: exactly 2*VV used; junk reads clamped
#define NBUK 64                 // stat buckets (de-contend global atomics)

typedef __attribute__((ext_vector_type(8))) short bf16x8;
typedef __attribute__((ext_vector_type(4))) float f32x4;

__device__ __forceinline__ unsigned short f2bf(float f) {
    unsigned u = __float_as_uint(f);
    return (unsigned short)((u + 0x7fffu + ((u >> 16) & 1u)) >> 16);  // RNE
}

// HW packed f32->bf16 (RNE), one instruction for a pair: lo -> bits[15:0]
__device__ __forceinline__ unsigned cvt_pk_bf16(float lo, float hi) {
    unsigned r;
    asm("v_cvt_pk_bf16_f32 %0, %1, %2" : "=v"(r) : "v"(lo), "v"(hi));
    return r;
}

// ---------------------------------------------------------------------------
// prep: Wflat[c][k=s*96+i] = bf16(0.2 * conv_w[(s*96+c)*96+i]);   // 1/WSZ folded in!
//       Bfr[f=s*2+nt][lane][j] = B-fragment of A_s for 16x16x32 MFMA
//       zbias[c*25+m] = sum_s cb[s*96+c] * sum_n A[s,n,m];  (UNscaled; ×cnt/5 at use)
//       stats[0 .. NBUK*192) = 0.   (per bucket: [0..95]=ssum, [96..191]=ssq)
// ---------------------------------------------------------------------------
__global__ __launch_bounds__(256) void prep(
    const float* __restrict__ conv_w, const float* __restrict__ A,
    const float* __restrict__ cb,
    __hip_bfloat16* __restrict__ Wflat,   // [96][288]
    __hip_bfloat16* __restrict__ Bfr,     // [6][64][8]
    float* __restrict__ zbias,            // [2400]
    float* __restrict__ stats)            // [NBUK*192]
{
    int id = blockIdx.x*256 + threadIdx.x;
    if (id < 27648) {
        int c = id / KK, k = id - c*KK;
        int s = k / CIN, i = k - s*CIN;
        Wflat[id] = __float2bfloat16(0.2f * conv_w[(s*COUT + c)*CIN + i]);
    } else if (id < 27648 + 3072) {
        int e = id - 27648;               // f*512 + l*8 + j
        int f = e >> 9, rem = e & 511;
        int l = rem >> 3, j = rem & 7;
        int s = f >> 1, nt = f & 1;
        int n = (l >> 4)*8 + j;
        int m = nt*16 + (l & 15);
        float v = (n < VV && m < VV) ? A[(s*VV + n)*VV + m] : 0.0f;
        Bfr[e] = __float2bfloat16(v);
    } else if (id < 27648 + 3072 + 2400) {
        int e = id - 27648 - 3072;
        int c = e / VV, m = e - c*VV;
        float v = 0.f;
        #pragma unroll
        for (int s = 0; s < SS; ++s) {
            float sa = 0.f;
            #pragma unroll
            for (int n = 0; n < VV; ++n) sa += A[(s*VV + n)*VV + m];
            v = fmaf(cb[s*COUT + c], sa, v);
        }
        zbias[e] = v;
    } else if (id < 27648 + 3072 + 2400 + NBUK*192) {
        stats[id - 27648 - 3072 - 2400] = 0.0f;
    }
}

// ---------------------------------------------------------------------------
// fused: per (b, t-tile of 2). Window-5 applied AT THE x LOAD; even/odd lane
// pairing: each lane loads only taps {t-2, t, t+2} (block-uniform edge
// guards) and swaps the 2-tap partial its partner needs via __shfl_xor(.,1).
// All f32->bf16 conversions use v_cvt_pk_bf16_f32. Phase 2 register-double-
// buffers afrag (L2/L1) and bfrag (LDS) across the 9-iter K-loop (depth-1 —
// measured best), with s_setprio(1) around the MFMA cluster (co-resident
// blocks sit in different phases -> scheduler role-split, T5 regime).
// out is written with NONTEMPORAL stores: out is write-once here, and its
// 92 MB of write-allocate was evicting x (88.5 MB) from L2/L3 -> the 49 MB
// HBM re-fetch of x seen in FETCH_SIZE. nt keeps x cache-resident.
// BN sum/sumsq reduced in the epilogue -> bucketed global atomics (NBUK).
// XCD-chunked swizzle: tiles r*18..r*18+17 all land on XCD r (144 = 8*18).
// ---------------------------------------------------------------------------
__global__ __launch_bounds__(256) void fused(
    const float* __restrict__ x,
    const __hip_bfloat16* __restrict__ Wflat,
    const __hip_bfloat16* __restrict__ Bfr,
    const float* __restrict__ zbias,
    float* __restrict__ out,
    float* __restrict__ stats)            // [NBUK][192]
{
    __shared__ __hip_bfloat16 XAt[XCOLS*KK];  // 28,800 B
    __shared__ float sh_stats[2][192];        // slot = nh; plain stores, fully covered
    const int tid  = threadIdx.x;
    const int lane = tid & 63;
    const int wave = tid >> 6;
    const int quad = lane >> 4;       // 0..3
    const int lrow = lane & 15;
    const int px   = blockIdx.x;      // 0..143
    const int tile = ((px & 7) * 18) + (px >> 3);   // XCD-chunked, bijective
    const int b    = blockIdx.y;      // 0..31
    const int t0   = tile*2;

    // 6 B1 fragments (A_s matrices), precomputed per-lane by prep
    bf16x8 bf1[6];
    #pragma unroll
    for (int f = 0; f < 6; ++f)
        bf1[f] = *(const bf16x8*)(Bfr + (f*64 + lane)*8);

    // ---- phase 1: wave w handles M-tiles 3w..3w+2 (rows = i*2+tl)
    #pragma unroll
    for (int mt3 = 0; mt3 < 3; ++mt3) {
        const int Mtile = wave*3 + mt3;
        const int arow = Mtile*16 + lrow;
        const int ai = arow >> 1, atl = arow & 1;
        const int t  = t0 + atl;
        const float* xr = x + ((size_t)(b*CIN + ai)*TT + t)*VV;
        float l0[8], l1[8], l2[8];
        if (quad < 3) {
            const int off = quad*8;
            #pragma unroll
            for (int j = 0; j < 8; ++j) l1[j] = xr[off + j];
            if (tile != 0) {
                #pragma unroll
                for (int j = 0; j < 8; ++j) l0[j] = xr[-2*VV + off + j];
            } else {
                #pragma unroll
                for (int j = 0; j < 8; ++j) l0[j] = 0.f;
            }
            if (tile != TT/2 - 1) {
                #pragma unroll
                for (int j = 0; j < 8; ++j) l2[j] = xr[2*VV + off + j];
            } else {
                #pragma unroll
                for (int j = 0; j < 8; ++j) l2[j] = 0.f;
            }
        } else {
            #pragma unroll
            for (int j = 0; j < 8; ++j) { l0[j] = 0.f; l1[j] = 0.f; l2[j] = 0.f; }
            l1[0] = xr[24];                                  // n=24; k=25..31 hit zero B
            if (tile != 0)        l0[0] = xr[-2*VV + 24];
            if (tile != TT/2 - 1) l2[0] = xr[ 2*VV + 24];
        }
        // window-5 via pair exchange: xw = (l0+l1+l2) + partner 2-tap partial
        float xv[8];
        #pragma unroll
        for (int j = 0; j < 8; ++j) {
            const float s    = l0[j] + l1[j] + l2[j];
            const float give = atl ? (l0[j] + l1[j]) : (l1[j] + l2[j]);
            const float recv = __shfl_xor(give, 1, 64);
            xv[j] = s + recv;
        }
        bf16x8 af;
        #pragma unroll
        for (int j2 = 0; j2 < 4; ++j2)
            ((unsigned*)&af)[j2] = cvt_pk_bf16(xv[2*j2], xv[2*j2 + 1]);

        // D rows owned by this lane: row16 = quad*4 + r ; i0 = Mtile*8+quad*2
        const int i0 = Mtile*8 + quad*2;
        #pragma unroll
        for (int s = 0; s < SS; ++s) {
            #pragma unroll
            for (int nt = 0; nt < 2; ++nt) {
                f32x4 d = {0.f, 0.f, 0.f, 0.f};
                d = __builtin_amdgcn_mfma_f32_16x16x32_bf16(af, bf1[s*2+nt], d, 0, 0, 0);
                const int m = nt*16 + lrow;
                if (m < VV) {
                    const int k0 = s*CIN + i0;         // even
                    const int g  = k0 >> 3, o = k0 & 7;
                    #pragma unroll
                    for (int tl = 0; tl < 2; ++tl) {   // pair (d[tl], d[tl+2]) -> (i0, i0+1)
                        const int col = tl*VV + m;
                        const int gs  = (g & ~3) | ((g & 3) ^ ((col >> 1) & 3));
                        const unsigned pv = cvt_pk_bf16(d[tl], d[tl+2]);
                        ((unsigned int*)XAt)[(col*KK + gs*8 + o) >> 1] = pv;
                    }
                }
            }
        }
    }
    __syncthreads();

    // ---- phase 2: wave split 2x2: mh -> c-tiles, nh -> col-tiles.
    // Depth-1 register double-buffer (measured best).
    const int mh = wave & 1, nh = wave >> 1;
    const int clr0 = ((nh*2 + 0)*16 + lrow < 2*VV) ? (nh*2+0)*16+lrow : 2*VV-1;
    const int clr1 = ((nh*2 + 1)*16 + lrow < 2*VV) ? (nh*2+1)*16+lrow : 2*VV-1;
    const int bx0  = quad ^ ((clr0 >> 1) & 3);
    const int bx1  = quad ^ ((clr1 >> 1) & 3);
    const __hip_bfloat16* wbase = Wflat + ((mh*3)*16 + lrow)*KK + quad*8;

    f32x4 acc[3][2] = {};
    bf16x8 aN[3], bN[2];
    #pragma unroll
    for (int mt = 0; mt < 3; ++mt) aN[mt] = *(const bf16x8*)(wbase + mt*16*KK);
    bN[0] = *(const bf16x8*)&XAt[clr0*KK + bx0*8];
    bN[1] = *(const bf16x8*)&XAt[clr1*KK + bx1*8];

    for (int it = 0; it < 9; ++it) {
        bf16x8 aC[3] = {aN[0], aN[1], aN[2]};
        bf16x8 bC[2] = {bN[0], bN[1]};
        if (it < 8) {
            const int k1 = (it+1)*32;
            #pragma unroll
            for (int mt = 0; mt < 3; ++mt) aN[mt] = *(const bf16x8*)(wbase + mt*16*KK + k1);
            bN[0] = *(const bf16x8*)&XAt[clr0*KK + ((it+1)*4 + bx0)*8];
            bN[1] = *(const bf16x8*)&XAt[clr1*KK + ((it+1)*4 + bx1)*8];
        }
        __builtin_amdgcn_s_setprio(1);
        #pragma unroll
        for (int mt = 0; mt < 3; ++mt) {
            #pragma unroll
            for (int ct = 0; ct < 2; ++ct)
                acc[mt][ct] = __builtin_amdgcn_mfma_f32_16x16x32_bf16(
                    aC[mt], bC[ct], acc[mt][ct], 0, 0, 0);
        }
        __builtin_amdgcn_s_setprio(0);
    }

    // ---- epilogue: D col = lane&15, row = quad*4+r ; nt-scatter + zbias*cnt/5,
    //      and accumulate per-channel sum / sumsq for BN.
    float ps[12], pq[12];
    #pragma unroll
    for (int i = 0; i < 12; ++i) { ps[i] = 0.f; pq[i] = 0.f; }

    #pragma unroll
    for (int ct = 0; ct < 2; ++ct) {
        const int cl = (nh*2 + ct)*16 + lrow;
        if (cl < 2*VV) {
            const int tl = (cl >= VV) ? 1 : 0;
            const int m  = cl - tl*VV;
            const int t  = t0 + tl;
            const int lo = (t-2 < 0) ? 0 : t-2;
            const int hi = (t+2 > TT-1) ? TT-1 : t+2;
            const float zs = (float)(hi - lo + 1) * 0.2f;   // cnt/5
            float* obase = out + ((size_t)b*COUT*TT + t)*VV + m;
            #pragma unroll
            for (int mt = 0; mt < 3; ++mt) {
                const int cbase = (mh*3 + mt)*16 + quad*4;
                #pragma unroll
                for (int r = 0; r < 4; ++r) {
                    const int c = cbase + r;
                    const float v = acc[mt][ct][r] + zbias[c*VV + m] * zs;
                    __builtin_nontemporal_store(v, obase + (size_t)c*TV);
                    ps[mt*4 + r] += v;
                    pq[mt*4 + r] = fmaf(v, v, pq[mt*4 + r]);
                }
            }
        }
    }

    // reduce over the 16 lanes of each quad group (channel is lrow-invariant)
    #pragma unroll
    for (int off = 1; off < 16; off <<= 1) {
        #pragma unroll
        for (int i = 0; i < 12; ++i) {
            ps[i] += __shfl_xor(ps[i], off, 64);
            pq[i] += __shfl_xor(pq[i], off, 64);
        }
    }
    // plain LDS stores: slot nh; waves mh=0/1 cover channels 0..47 / 48..95
    if (lrow == 0) {
        #pragma unroll
        for (int i = 0; i < 12; ++i) {
            const int c = (mh*3 + (i >> 2))*16 + quad*4 + (i & 3);
            sh_stats[nh][c]      = ps[i];
            sh_stats[nh][96 + c] = pq[i];
        }
    }
    __syncthreads();
    if (tid < 192) {
        const int bucket = (px + b) & (NBUK - 1);
        atomicAdd(&stats[bucket*192 + tid], sh_stats[0][tid] + sh_stats[1][tid]);
    }
}

// ---------------------------------------------------------------------------
// k4: reduce the NBUK stat buckets for this channel, then stream normalize +
// relu in place, two independent float4 halves per iteration, all accesses
// NONTEMPORAL (one-touch stream; keeps x resident in L3 across iterations).
// ---------------------------------------------------------------------------
__global__ __launch_bounds__(256) void k4_norm(
    float* __restrict__ buf, const float* __restrict__ stats,
    const float* __restrict__ gamma, const float* __restrict__ beta)
{
    const int tid  = threadIdx.x;
    const int slab = blockIdx.x;              // b*COUT + c
    const int c    = slab % COUT;
    float s0 = 0.f, s1 = 0.f;
    #pragma unroll 16
    for (int u = 0; u < NBUK; ++u) {
        s0 += stats[u*192 + c];
        s1 += stats[u*192 + 96 + c];
    }
    const float invN = 1.0f / (float)(BB * TV);
    const float mean = s0 * invN;
    const float var  = s1 * invN - mean * mean;
    const float inv  = rsqrtf(var + BN_EPS);
    const float sc   = gamma[c] * inv;
    const float bi   = beta[c] - mean * sc;
    f32x4* p = (f32x4*)(buf + (size_t)slab * TV);
    // TV/4 = 1800 float4 = 2 halves of 900
    for (int u = tid; u < 900; u += 256) {
        f32x4 v0 = __builtin_nontemporal_load(p + u);
        f32x4 v1 = __builtin_nontemporal_load(p + u + 900);
        #pragma unroll
        for (int jj = 0; jj < 4; ++jj) {
            v0[jj] = fmaxf(fmaf(v0[jj], sc, bi), 0.0f);
            v1[jj] = fmaxf(fmaf(v1[jj], sc, bi), 0.0f);
        }
        __builtin_nontemporal_store(v0, p + u);
        __builtin_nontemporal_store(v1, p + u + 900);
    }
}

extern "C" void kernel_launch(void* const* d_in, const int* in_sizes, int n_in,
                              void* d_out, int out_size, void* d_ws, size_t ws_size,
                              hipStream_t stream) {
    const float* x      = (const float*)d_in[0];
    const float* A      = (const float*)d_in[1];
    const float* conv_w = (const float*)d_in[2];
    const float* conv_b = (const float*)d_in[3];
    const float* gamma  = (const float*)d_in[4];
    const float* beta   = (const float*)d_in[5];
    float* out = (float*)d_out;

    // ws layout: zbias(2400 f) | stats(NBUK*192 f) | Wflat (27648 bf16) | Bfr (3072 bf16)
    float* zbias = (float*)d_ws;
    float* stats = zbias + 2400;
    __hip_bfloat16* Wflat = (__hip_bfloat16*)(stats + NBUK*192);
    __hip_bfloat16* Bfr   = Wflat + (size_t)COUT * KK;

    // prep thread count: 27648 + 3072 + 2400 + NBUK*192 = 45,408 -> 178 blocks
    prep   <<<dim3(178),      dim3(256), 0, stream>>>(conv_w, A, conv_b, Wflat, Bfr, zbias, stats);
    fused  <<<dim3(TT/2, BB), dim3(256), 0, stream>>>(x, Wflat, Bfr, zbias, out, stats);
    k4_norm<<<dim3(BB*COUT),  dim3(256), 0, stream>>>(out, stats, gamma, beta);
}

// Round 11
// 262.058 us; speedup vs baseline: 1.0866x; 1.0866x over previous
//
#include <hip/hip_runtime.h>
#include <hip/hip_bf16.h>

// Problem constants
#define BB 32
#define CIN 96
#define TT 288
#define VV 25
#define SS 3
#define COUT 96
#define WSZ 5
#define BN_EPS 1e-5f
#define TV (TT*VV)              // 7200
#define KK 288                  // fused GEMM K = s*96+i
#define XCOLS 50                // XAtile rows: exactly 2*VV used; junk reads clamped
#define NBUK 64                 // stat buckets (de-contend global atomics)

typedef __attribute__((ext_vector_type(8))) short bf16x8;
typedef __attribute__((ext_vector_type(4))) float f32x4;

__device__ __forceinline__ unsigned short f2bf(float f) {
    unsigned u = __float_as_uint(f);
    return (unsigned short)((u + 0x7fffu + ((u >> 16) & 1u)) >> 16);  // RNE
}

// HW packed f32->bf16 (RNE), one instruction for a pair: lo -> bits[15:0]
__device__ __forceinline__ unsigned cvt_pk_bf16(float lo, float hi) {
    unsigned r;
    asm("v_cvt_pk_bf16_f32 %0, %1, %2" : "=v"(r) : "v"(lo), "v"(hi));
    return r;
}

// ---------------------------------------------------------------------------
// prep: Wflat[c][k=s*96+i] = bf16(0.2 * conv_w[(s*96+c)*96+i]);   // 1/WSZ folded in!
//       Bfr[f=s*2+nt][lane][j] = B-fragment of A_s for 16x16x32 MFMA
//       zbias[c*25+m] = sum_s cb[s*96+c] * sum_n A[s,n,m];  (UNscaled; ×cnt/5 at use)
//       stats[0 .. NBUK*192) = 0.   (per bucket: [0..95]=ssum, [96..191]=ssq)
// ---------------------------------------------------------------------------
__global__ __launch_bounds__(256) void prep(
    const float* __restrict__ conv_w, const float* __restrict__ A,
    const float* __restrict__ cb,
    __hip_bfloat16* __restrict__ Wflat,   // [96][288]
    __hip_bfloat16* __restrict__ Bfr,     // [6][64][8]
    float* __restrict__ zbias,            // [2400]
    float* __restrict__ stats)            // [NBUK*192]
{
    int id = blockIdx.x*256 + threadIdx.x;
    if (id < 27648) {
        int c = id / KK, k = id - c*KK;
        int s = k / CIN, i = k - s*CIN;
        Wflat[id] = __float2bfloat16(0.2f * conv_w[(s*COUT + c)*CIN + i]);
    } else if (id < 27648 + 3072) {
        int e = id - 27648;               // f*512 + l*8 + j
        int f = e >> 9, rem = e & 511;
        int l = rem >> 3, j = rem & 7;
        int s = f >> 1, nt = f & 1;
        int n = (l >> 4)*8 + j;
        int m = nt*16 + (l & 15);
        float v = (n < VV && m < VV) ? A[(s*VV + n)*VV + m] : 0.0f;
        Bfr[e] = __float2bfloat16(v);
    } else if (id < 27648 + 3072 + 2400) {
        int e = id - 27648 - 3072;
        int c = e / VV, m = e - c*VV;
        float v = 0.f;
        #pragma unroll
        for (int s = 0; s < SS; ++s) {
            float sa = 0.f;
            #pragma unroll
            for (int n = 0; n < VV; ++n) sa += A[(s*VV + n)*VV + m];
            v = fmaf(cb[s*COUT + c], sa, v);
        }
        zbias[e] = v;
    } else if (id < 27648 + 3072 + 2400 + NBUK*192) {
        stats[id - 27648 - 3072 - 2400] = 0.0f;
    }
}

// ---------------------------------------------------------------------------
// fused: per (b, t-tile of 2). Window-5 applied AT THE x LOAD; even/odd lane
// pairing: each lane loads only taps {t-2, t, t+2} (block-uniform edge
// guards) and swaps the 2-tap partial its partner needs via __shfl_xor(.,1).
// All f32->bf16 conversions use v_cvt_pk_bf16_f32. Phase 2 register-double-
// buffers afrag (L2/L1) and bfrag (LDS) across the 9-iter K-loop (depth-1 —
// measured best; deeper pipelines, persistent variants, and nontemporal
// stores all regressed: nt stores doubled WRITE_SIZE via partial-line
// write-through and killed k4's L3 reuse of z).
// BN sum/sumsq reduced in the epilogue -> bucketed global atomics (NBUK).
// XCD-chunked swizzle: tiles r*18..r*18+17 all land on XCD r (144 = 8*18).
// FETCH ~49 MB is compulsory (harness re-poisons inputs per iteration).
// ---------------------------------------------------------------------------
__global__ __launch_bounds__(256) void fused(
    const float* __restrict__ x,
    const __hip_bfloat16* __restrict__ Wflat,
    const __hip_bfloat16* __restrict__ Bfr,
    const float* __restrict__ zbias,
    float* __restrict__ out,
    float* __restrict__ stats)            // [NBUK][192]
{
    __shared__ __hip_bfloat16 XAt[XCOLS*KK];  // 28,800 B
    __shared__ float sh_stats[2][192];        // slot = nh; plain stores, fully covered
    const int tid  = threadIdx.x;
    const int lane = tid & 63;
    const int wave = tid >> 6;
    const int quad = lane >> 4;       // 0..3
    const int lrow = lane & 15;
    const int px   = blockIdx.x;      // 0..143
    const int tile = ((px & 7) * 18) + (px >> 3);   // XCD-chunked, bijective
    const int b    = blockIdx.y;      // 0..31
    const int t0   = tile*2;

    // 6 B1 fragments (A_s matrices), precomputed per-lane by prep
    bf16x8 bf1[6];
    #pragma unroll
    for (int f = 0; f < 6; ++f)
        bf1[f] = *(const bf16x8*)(Bfr + (f*64 + lane)*8);

    // ---- phase 1: wave w handles M-tiles 3w..3w+2 (rows = i*2+tl)
    #pragma unroll
    for (int mt3 = 0; mt3 < 3; ++mt3) {
        const int Mtile = wave*3 + mt3;
        const int arow = Mtile*16 + lrow;
        const int ai = arow >> 1, atl = arow & 1;
        const int t  = t0 + atl;
        const float* xr = x + ((size_t)(b*CIN + ai)*TT + t)*VV;
        float l0[8], l1[8], l2[8];
        if (quad < 3) {
            const int off = quad*8;
            #pragma unroll
            for (int j = 0; j < 8; ++j) l1[j] = xr[off + j];
            if (tile != 0) {
                #pragma unroll
                for (int j = 0; j < 8; ++j) l0[j] = xr[-2*VV + off + j];
            } else {
                #pragma unroll
                for (int j = 0; j < 8; ++j) l0[j] = 0.f;
            }
            if (tile != TT/2 - 1) {
                #pragma unroll
                for (int j = 0; j < 8; ++j) l2[j] = xr[2*VV + off + j];
            } else {
                #pragma unroll
                for (int j = 0; j < 8; ++j) l2[j] = 0.f;
            }
        } else {
            #pragma unroll
            for (int j = 0; j < 8; ++j) { l0[j] = 0.f; l1[j] = 0.f; l2[j] = 0.f; }
            l1[0] = xr[24];                                  // n=24; k=25..31 hit zero B
            if (tile != 0)        l0[0] = xr[-2*VV + 24];
            if (tile != TT/2 - 1) l2[0] = xr[ 2*VV + 24];
        }
        // window-5 via pair exchange: xw = (l0+l1+l2) + partner 2-tap partial
        float xv[8];
        #pragma unroll
        for (int j = 0; j < 8; ++j) {
            const float s    = l0[j] + l1[j] + l2[j];
            const float give = atl ? (l0[j] + l1[j]) : (l1[j] + l2[j]);
            const float recv = __shfl_xor(give, 1, 64);
            xv[j] = s + recv;
        }
        bf16x8 af;
        #pragma unroll
        for (int j2 = 0; j2 < 4; ++j2)
            ((unsigned*)&af)[j2] = cvt_pk_bf16(xv[2*j2], xv[2*j2 + 1]);

        // D rows owned by this lane: row16 = quad*4 + r ; i0 = Mtile*8+quad*2
        const int i0 = Mtile*8 + quad*2;
        #pragma unroll
        for (int s = 0; s < SS; ++s) {
            #pragma unroll
            for (int nt = 0; nt < 2; ++nt) {
                f32x4 d = {0.f, 0.f, 0.f, 0.f};
                d = __builtin_amdgcn_mfma_f32_16x16x32_bf16(af, bf1[s*2+nt], d, 0, 0, 0);
                const int m = nt*16 + lrow;
                if (m < VV) {
                    const int k0 = s*CIN + i0;         // even
                    const int g  = k0 >> 3, o = k0 & 7;
                    #pragma unroll
                    for (int tl = 0; tl < 2; ++tl) {   // pair (d[tl], d[tl+2]) -> (i0, i0+1)
                        const int col = tl*VV + m;
                        const int gs  = (g & ~3) | ((g & 3) ^ ((col >> 1) & 3));
                        const unsigned pv = cvt_pk_bf16(d[tl], d[tl+2]);
                        ((unsigned int*)XAt)[(col*KK + gs*8 + o) >> 1] = pv;
                    }
                }
            }
        }
    }
    __syncthreads();

    // ---- phase 2: wave split 2x2: mh -> c-tiles, nh -> col-tiles.
    // Depth-1 register double-buffer (measured best).
    const int mh = wave & 1, nh = wave >> 1;
    const int clr0 = ((nh*2 + 0)*16 + lrow < 2*VV) ? (nh*2+0)*16+lrow : 2*VV-1;
    const int clr1 = ((nh*2 + 1)*16 + lrow < 2*VV) ? (nh*2+1)*16+lrow : 2*VV-1;
    const int bx0  = quad ^ ((clr0 >> 1) & 3);
    const int bx1  = quad ^ ((clr1 >> 1) & 3);
    const __hip_bfloat16* wbase = Wflat + ((mh*3)*16 + lrow)*KK + quad*8;

    f32x4 acc[3][2] = {};
    bf16x8 aN[3], bN[2];
    #pragma unroll
    for (int mt = 0; mt < 3; ++mt) aN[mt] = *(const bf16x8*)(wbase + mt*16*KK);
    bN[0] = *(const bf16x8*)&XAt[clr0*KK + bx0*8];
    bN[1] = *(const bf16x8*)&XAt[clr1*KK + bx1*8];

    for (int it = 0; it < 9; ++it) {
        bf16x8 aC[3] = {aN[0], aN[1], aN[2]};
        bf16x8 bC[2] = {bN[0], bN[1]};
        if (it < 8) {
            const int k1 = (it+1)*32;
            #pragma unroll
            for (int mt = 0; mt < 3; ++mt) aN[mt] = *(const bf16x8*)(wbase + mt*16*KK + k1);
            bN[0] = *(const bf16x8*)&XAt[clr0*KK + ((it+1)*4 + bx0)*8];
            bN[1] = *(const bf16x8*)&XAt[clr1*KK + ((it+1)*4 + bx1)*8];
        }
        #pragma unroll
        for (int mt = 0; mt < 3; ++mt) {
            #pragma unroll
            for (int ct = 0; ct < 2; ++ct)
                acc[mt][ct] = __builtin_amdgcn_mfma_f32_16x16x32_bf16(
                    aC[mt], bC[ct], acc[mt][ct], 0, 0, 0);
        }
    }

    // ---- epilogue: D col = lane&15, row = quad*4+r ; scatter + zbias*cnt/5,
    //      and accumulate per-channel sum / sumsq for BN.
    float ps[12], pq[12];
    #pragma unroll
    for (int i = 0; i < 12; ++i) { ps[i] = 0.f; pq[i] = 0.f; }

    #pragma unroll
    for (int ct = 0; ct < 2; ++ct) {
        const int cl = (nh*2 + ct)*16 + lrow;
        if (cl < 2*VV) {
            const int tl = (cl >= VV) ? 1 : 0;
            const int m  = cl - tl*VV;
            const int t  = t0 + tl;
            const int lo = (t-2 < 0) ? 0 : t-2;
            const int hi = (t+2 > TT-1) ? TT-1 : t+2;
            const float zs = (float)(hi - lo + 1) * 0.2f;   // cnt/5
            float* obase = out + ((size_t)b*COUT*TT + t)*VV + m;
            #pragma unroll
            for (int mt = 0; mt < 3; ++mt) {
                const int cbase = (mh*3 + mt)*16 + quad*4;
                #pragma unroll
                for (int r = 0; r < 4; ++r) {
                    const int c = cbase + r;
                    const float v = acc[mt][ct][r] + zbias[c*VV + m] * zs;
                    obase[(size_t)c*TV] = v;
                    ps[mt*4 + r] += v;
                    pq[mt*4 + r] = fmaf(v, v, pq[mt*4 + r]);
                }
            }
        }
    }

    // reduce over the 16 lanes of each quad group (channel is lrow-invariant)
    #pragma unroll
    for (int off = 1; off < 16; off <<= 1) {
        #pragma unroll
        for (int i = 0; i < 12; ++i) {
            ps[i] += __shfl_xor(ps[i], off, 64);
            pq[i] += __shfl_xor(pq[i], off, 64);
        }
    }
    // plain LDS stores: slot nh; waves mh=0/1 cover channels 0..47 / 48..95
    if (lrow == 0) {
        #pragma unroll
        for (int i = 0; i < 12; ++i) {
            const int c = (mh*3 + (i >> 2))*16 + quad*4 + (i & 3);
            sh_stats[nh][c]      = ps[i];
            sh_stats[nh][96 + c] = pq[i];
        }
    }
    __syncthreads();
    if (tid < 192) {
        const int bucket = (px + b) & (NBUK - 1);
        atomicAdd(&stats[bucket*192 + tid], sh_stats[0][tid] + sh_stats[1][tid]);
    }
}

// ---------------------------------------------------------------------------
// k4: reduce the NBUK stat buckets for this channel (uniform scalar loads,
// deep unroll to batch them), then stream normalize + relu in place with TWO
// independent float4 halves per iteration (2 loads in flight per wave).
// ---------------------------------------------------------------------------
__global__ __launch_bounds__(256) void k4_norm(
    float* __restrict__ buf, const float* __restrict__ stats,
    const float* __restrict__ gamma, const float* __restrict__ beta)
{
    const int tid  = threadIdx.x;
    const int slab = blockIdx.x;              // b*COUT + c
    const int c    = slab % COUT;
    float s0 = 0.f, s1 = 0.f;
    #pragma unroll 16
    for (int u = 0; u < NBUK; ++u) {
        s0 += stats[u*192 + c];
        s1 += stats[u*192 + 96 + c];
    }
    const float invN = 1.0f / (float)(BB * TV);
    const float mean = s0 * invN;
    const float var  = s1 * invN - mean * mean;
    const float inv  = rsqrtf(var + BN_EPS);
    const float sc   = gamma[c] * inv;
    const float bi   = beta[c] - mean * sc;
    float4* p = (float4*)(buf + (size_t)slab * TV);
    // TV/4 = 1800 float4 = 2 halves of 900
    for (int u = tid; u < 900; u += 256) {
        float4 v0 = p[u];
        float4 v1 = p[u + 900];
        v0.x = fmaxf(fmaf(v0.x, sc, bi), 0.0f);
        v0.y = fmaxf(fmaf(v0.y, sc, bi), 0.0f);
        v0.z = fmaxf(fmaf(v0.z, sc, bi), 0.0f);
        v0.w = fmaxf(fmaf(v0.w, sc, bi), 0.0f);
        v1.x = fmaxf(fmaf(v1.x, sc, bi), 0.0f);
        v1.y = fmaxf(fmaf(v1.y, sc, bi), 0.0f);
        v1.z = fmaxf(fmaf(v1.z, sc, bi), 0.0f);
        v1.w = fmaxf(fmaf(v1.w, sc, bi), 0.0f);
        p[u]       = v0;
        p[u + 900] = v1;
    }
}

extern "C" void kernel_launch(void* const* d_in, const int* in_sizes, int n_in,
                              void* d_out, int out_size, void* d_ws, size_t ws_size,
                              hipStream_t stream) {
    const float* x      = (const float*)d_in[0];
    const float* A      = (const float*)d_in[1];
    const float* conv_w = (const float*)d_in[2];
    const float* conv_b = (const float*)d_in[3];
    const float* gamma  = (const float*)d_in[4];
    const float* beta   = (const float*)d_in[5];
    float* out = (float*)d_out;

    // ws layout: zbias(2400 f) | stats(NBUK*192 f) | Wflat (27648 bf16) | Bfr (3072 bf16)
    float* zbias = (float*)d_ws;
    float* stats = zbias + 2400;
    __hip_bfloat16* Wflat = (__hip_bfloat16*)(stats + NBUK*192);
    __hip_bfloat16* Bfr   = Wflat + (size_t)COUT * KK;

    // prep thread count: 27648 + 3072 + 2400 + NBUK*192 = 45,408 -> 178 blocks
    prep   <<<dim3(178),      dim3(256), 0, stream>>>(conv_w, A, conv_b, Wflat, Bfr, zbias, stats);
    fused  <<<dim3(TT/2, BB), dim3(256), 0, stream>>>(x, Wflat, Bfr, zbias, out, stats);
    k4_norm<<<dim3(BB*COUT),  dim3(256), 0, stream>>>(out, stats, gamma, beta);
}